// Round 1
// baseline (1899.398 us; speedup 1.0000x reference)
//
#include <hip/hip_runtime.h>

#define TPB 256

__device__ __forceinline__ float leaky02(float x){ return x > 0.f ? x : 0.2f*x; }

// ---------------- exclusive prefix scan (hierarchical) ----------------
__global__ void k_scan_tile(const int* __restrict__ in, int* __restrict__ out,
                            int* __restrict__ bsum, int n) {
  __shared__ int sh[TPB];
  int t = threadIdx.x;
  int base = blockIdx.x * (TPB*4) + t*4;
  int v0=0,v1=0,v2=0,v3=0;
  if (base+0 < n) v0 = in[base+0];
  if (base+1 < n) v1 = in[base+1];
  if (base+2 < n) v2 = in[base+2];
  if (base+3 < n) v3 = in[base+3];
  int tsum = v0+v1+v2+v3;
  sh[t] = tsum; __syncthreads();
  for (int off=1; off<TPB; off<<=1){
    int x = (t>=off) ? sh[t-off] : 0;
    __syncthreads();
    sh[t] += x;
    __syncthreads();
  }
  int incl = sh[t];
  int excl = incl - tsum;
  if (t == TPB-1) bsum[blockIdx.x] = incl;
  int run = excl;
  if (base+0 < n){ out[base+0] = run; run += v0; }
  if (base+1 < n){ out[base+1] = run; run += v1; }
  if (base+2 < n){ out[base+2] = run; run += v2; }
  if (base+3 < n){ out[base+3] = run; run += v3; }
}

__global__ void k_scan_small(int* __restrict__ a, int n) {
  __shared__ int sh[TPB];
  __shared__ int carry;
  int t = threadIdx.x;
  if (t==0) carry = 0;
  __syncthreads();
  for (int base=0; base<n; base+=TPB){
    int v = (base+t < n) ? a[base+t] : 0;
    sh[t] = v; __syncthreads();
    for (int off=1; off<TPB; off<<=1){
      int x = (t>=off)? sh[t-off]:0; __syncthreads();
      sh[t]+=x; __syncthreads();
    }
    int c0 = carry;
    if (base+t < n) a[base+t] = c0 + sh[t] - v;
    int tot = sh[TPB-1];
    __syncthreads();
    if (t==0) carry = c0 + tot;
    __syncthreads();
  }
}

__global__ void k_scan_add(int* __restrict__ out, const int* __restrict__ bsum,
                           int n, int total) {
  int i = blockIdx.x*TPB + threadIdx.x;
  if (i < n) out[i] += bsum[i >> 10];
  if (i == 0) out[n] = total;
}

// ---------------- counting + scatter (sort by segment) ----------------
__global__ void k_count_edges(const int* __restrict__ dst, const float* __restrict__ eattr,
                              int E, int* __restrict__ cnt, float* __restrict__ sum_attr){
  int e = blockIdx.x*TPB+threadIdx.x;
  if (e>=E) return;
  int d = dst[e];
  atomicAdd(&cnt[d], 1);
  float2 ea = ((const float2*)eattr)[e];
  atomicAdd(&sum_attr[2*d],   ea.x);
  atomicAdd(&sum_attr[2*d+1], ea.y);
}

__global__ void k_count_idx(const int* __restrict__ rows, int n, int* __restrict__ cnt){
  int i = blockIdx.x*TPB+threadIdx.x;
  if (i>=n) return;
  atomicAdd(&cnt[rows[i]], 1);
}

__global__ void k_scatter_edges(const int* __restrict__ src, const int* __restrict__ dst,
                                const float* __restrict__ eattr, int E,
                                const int* __restrict__ rs, int* __restrict__ fill,
                                int* __restrict__ src_sorted, float2* __restrict__ ea_sorted){
  int e = blockIdx.x*TPB+threadIdx.x;
  if (e>=E) return;
  int d = dst[e];
  int pos = rs[d] + atomicAdd(&fill[d],1);
  src_sorted[pos] = src[e];
  ea_sorted[pos] = ((const float2*)eattr)[e];
}

__global__ void k_scatter_pool(const int* __restrict__ rows, const int* __restrict__ cols,
                               const float* __restrict__ vals, int n,
                               const int* __restrict__ rs, int* __restrict__ fill,
                               int* __restrict__ col_sorted, float* __restrict__ val_sorted){
  int i = blockIdx.x*TPB+threadIdx.x;
  if (i>=n) return;
  int r = rows[i];
  int pos = rs[r] + atomicAdd(&fill[r],1);
  col_sorted[pos] = cols[i];
  val_sorted[pos] = vals[i];
}

// ---------------- per-node transform: xp = x@W, a_src, a_dst ----------------
__global__ __launch_bounds__(TPB) void k_node_pre1(
    const int* __restrict__ gid, const float* __restrict__ ord, const float* __restrict__ emb,
    const float* __restrict__ lin_w, const float* __restrict__ att_src, const float* __restrict__ att_dst,
    float* __restrict__ xp, float* __restrict__ asrc, float* __restrict__ adst, int N){
  __shared__ float W[20*32];
  __shared__ float As[32], Ad[32];
  for (int i=threadIdx.x; i<20*32; i+=TPB) W[i]=lin_w[i];
  if (threadIdx.x < 32){ As[threadIdx.x]=att_src[threadIdx.x]; Ad[threadIdx.x]=att_dst[threadIdx.x]; }
  __syncthreads();
  int n = blockIdx.x*TPB+threadIdx.x;
  if (n>=N) return;
  float x[20];
  int g = gid[n];
  #pragma unroll
  for (int k=0;k<16;k++) x[k]=emb[g*16+k];
  float4 o4 = ((const float4*)ord)[n];
  x[16]=o4.x; x[17]=o4.y; x[18]=o4.z; x[19]=o4.w;
  float acc[32];
  #pragma unroll
  for (int c=0;c<32;c++) acc[c]=0.f;
  #pragma unroll
  for (int k=0;k<20;k++){
    float xk=x[k];
    #pragma unroll
    for (int c=0;c<32;c++) acc[c] += xk*W[k*32+c];
  }
  float s0=0,s1=0,d0=0,d1=0;
  #pragma unroll
  for (int c=0;c<16;c++){
    s0+=acc[c]*As[c];      d0+=acc[c]*Ad[c];
    s1+=acc[16+c]*As[16+c]; d1+=acc[16+c]*Ad[16+c];
  }
  float4* xpo=(float4*)(xp + (size_t)n*32);
  #pragma unroll
  for (int q=0;q<8;q++) xpo[q]=make_float4(acc[4*q],acc[4*q+1],acc[4*q+2],acc[4*q+3]);
  asrc[2*n]=s0; asrc[2*n+1]=s1; adst[2*n]=d0; adst[2*n+1]=d1;
}

__global__ __launch_bounds__(TPB) void k_node_pre(
    const float* __restrict__ hin,
    const float* __restrict__ lin_w, const float* __restrict__ att_src, const float* __restrict__ att_dst,
    float* __restrict__ xp, float* __restrict__ asrc, float* __restrict__ adst, int N){
  __shared__ float W[32*32];
  __shared__ float As[32], Ad[32];
  for (int i=threadIdx.x; i<1024; i+=TPB) W[i]=lin_w[i];
  if (threadIdx.x < 32){ As[threadIdx.x]=att_src[threadIdx.x]; Ad[threadIdx.x]=att_dst[threadIdx.x]; }
  __syncthreads();
  int n = blockIdx.x*TPB+threadIdx.x;
  if (n>=N) return;
  float x[32];
  const float4* hi = (const float4*)(hin + (size_t)n*32);
  #pragma unroll
  for (int q=0;q<8;q++){ float4 v=hi[q]; x[4*q]=v.x; x[4*q+1]=v.y; x[4*q+2]=v.z; x[4*q+3]=v.w; }
  float acc[32];
  #pragma unroll
  for (int c=0;c<32;c++) acc[c]=0.f;
  #pragma unroll
  for (int k=0;k<32;k++){
    float xk=x[k];
    #pragma unroll
    for (int c=0;c<32;c++) acc[c] += xk*W[k*32+c];
  }
  float s0=0,s1=0,d0=0,d1=0;
  #pragma unroll
  for (int c=0;c<16;c++){
    s0+=acc[c]*As[c];       d0+=acc[c]*Ad[c];
    s1+=acc[16+c]*As[16+c]; d1+=acc[16+c]*Ad[16+c];
  }
  float4* xpo=(float4*)(xp + (size_t)n*32);
  #pragma unroll
  for (int q=0;q<8;q++) xpo[q]=make_float4(acc[4*q],acc[4*q+1],acc[4*q+2],acc[4*q+3]);
  asrc[2*n]=s0; asrc[2*n+1]=s1; adst[2*n]=d0; adst[2*n+1]=d1;
}

// ---------------- GAT aggregation: wave per node, fused softmax+agg+bias+relu ----------------
__global__ __launch_bounds__(TPB) void k_agg(
    const float* __restrict__ xp, const float* __restrict__ asrc, const float* __restrict__ adst,
    const int* __restrict__ rs, const int* __restrict__ src_sorted, const float2* __restrict__ ea_sorted,
    const int* __restrict__ cnt, const float2* __restrict__ sum_attr,
    const float* __restrict__ edge_w, const float* __restrict__ att_edge,
    const float* __restrict__ bias, float* __restrict__ hout, int N)
{
  int n = blockIdx.x*4 + (threadIdx.x>>6);
  if (n >= N) return;
  int lane = threadIdx.x & 63;
  int c = lane & 31;
  int sub = lane >> 5;
  int h = c >> 4;
  float we0 = 0.f, we1 = 0.f;
  #pragma unroll
  for (int cc=0; cc<16; ++cc){
    float ae = att_edge[h*16+cc];
    we0 += edge_w[h*16+cc]*ae;
    we1 += edge_w[32+h*16+cc]*ae;
  }
  float adn = adst[2*n+h];
  float acc = 0.f, den = 0.f;
  if (sub == 0){
    int cn = cnt[n];
    float inv = 1.0f / (float)(cn > 0 ? cn : 1);
    float2 sa = sum_attr[n];
    float al = asrc[2*n+h] + adn + sa.x*inv*we0 + sa.y*inv*we1;
    al = leaky02(al);
    float p = __expf(al);
    acc = p * xp[(size_t)n*32+c];
    den = p;
  }
  int jb = rs[n], je = rs[n+1];
  for (int j = jb + sub; j < je; j += 2){
    int s = src_sorted[j];
    float2 ea = ea_sorted[j];
    float al = asrc[2*s+h] + adn + ea.x*we0 + ea.y*we1;
    al = leaky02(al);
    float p = __expf(al);
    acc += p * xp[(size_t)s*32+c];
    den += p;
  }
  acc += __shfl_xor(acc, 32);
  den += __shfl_xor(den, 32);
  if (sub == 0){
    hout[(size_t)n*32+c] = fmaxf(acc/(den + 1e-16f) + bias[c], 0.0f);
  }
}

// ---------------- pooling + fused MLP head: wave per pooled row ----------------
__global__ __launch_bounds__(TPB) void k_pool_head(
    const float* __restrict__ h3, const int* __restrict__ rsP,
    const int* __restrict__ col_sorted, const float* __restrict__ val_sorted,
    const float* __restrict__ W1, const float* __restrict__ b1,
    const float* __restrict__ W2, const float* __restrict__ b2,
    float* __restrict__ out, int P){
  __shared__ float sW1[32*32];
  __shared__ float sb1[32], sW2[32];
  __shared__ float pool_s[4][32];
  for (int i=threadIdx.x;i<1024;i+=TPB) sW1[i]=W1[i];
  if (threadIdx.x<32){ sb1[threadIdx.x]=b1[threadIdx.x]; sW2[threadIdx.x]=W2[threadIdx.x]; }
  __syncthreads();
  int wslot = threadIdx.x >> 6;
  int lane = threadIdx.x & 63;
  int c = lane & 31, sub = lane >> 5;
  int p = blockIdx.x*4 + wslot;
  float acc = 0.f;
  if (p < P){
    int jb = rsP[p], je = rsP[p+1];
    for (int j=jb+sub; j<je; j+=2){
      int col = col_sorted[j];
      float v = val_sorted[j];
      acc += v * h3[(size_t)col*32 + c];
    }
  }
  acc += __shfl_xor(acc, 32);
  if (sub==0) pool_s[wslot][c] = acc;
  __syncthreads();
  if (p < P && sub==0){
    float hh = sb1[c];
    #pragma unroll
    for (int cc=0; cc<32; ++cc) hh += pool_s[wslot][cc]*sW1[cc*32+c];
    hh = fmaxf(hh, 0.f);
    float r = hh * sW2[c];
    #pragma unroll
    for (int m=16;m>=1;m>>=1) r += __shfl_xor(r, m);
    if (c==0) out[p] = r + b2[0];
  }
}

// ---------------- launch ----------------
extern "C" void kernel_launch(void* const* d_in, const int* in_sizes, int n_in,
                              void* d_out, int out_size, void* d_ws, size_t ws_size,
                              hipStream_t stream){
  const int*   group_ids = (const int*)d_in[0];
  const float* ord       = (const float*)d_in[1];
  const int*   eidx      = (const int*)d_in[2];
  const float* eattr     = (const float*)d_in[3];
  const int*   prow      = (const int*)d_in[4];
  const int*   pcol      = (const int*)d_in[5];
  const float* pval      = (const float*)d_in[6];
  const float* emb       = (const float*)d_in[8];
  const float* head_w1   = (const float*)d_in[27];
  const float* head_b1   = (const float*)d_in[28];
  const float* head_w2   = (const float*)d_in[29];
  const float* head_b2   = (const float*)d_in[30];

  int N   = in_sizes[0];
  int E   = in_sizes[2]/2;
  int NNZ = in_sizes[4];
  int P   = out_size;

  const int* src = eidx;
  const int* dst = eidx + E;

  char* w = (char*)d_ws;
  auto alloc = [&](size_t bytes)->char*{ char* p=w; w += (bytes+255)&~255ull; return p; };
  int*    cnt        = (int*)   alloc(4ull*N);
  int*    fill       = (int*)   alloc(4ull*N);
  int*    rs         = (int*)   alloc(4ull*(N+1));
  float*  sum_attr   = (float*) alloc(8ull*N);
  int*    bsum       = (int*)   alloc(4ull*4096);
  int*    src_sorted = (int*)   alloc(4ull*E);
  float2* ea_sorted  = (float2*)alloc(8ull*E);
  float*  xp         = (float*) alloc(4ull*32*N);
  float*  asrc       = (float*) alloc(8ull*N);
  float*  adst       = (float*) alloc(8ull*N);
  float*  hbuf       = (float*) alloc(4ull*32*N);

  // pool-sort arrays alias regions dead after layer-3 aggregation
  int*   cntP       = (int*)xp;
  int*   fillP      = cntP + P;
  int*   rsP        = fillP + P;              // fits: 3*P*4 = 2.4MB << 12.8MB
  int*   col_sorted = src_sorted;             // 4*NNZ == 4*E
  float* val_sorted = (float*)ea_sorted;      // 4*NNZ <= 8*E

  int gE = (E+TPB-1)/TPB, gN = (N+TPB-1)/TPB, gZ = (NNZ+TPB-1)/TPB, gP = (P+TPB-1)/TPB;

  // ---- build dst-sorted edge structure (reused by all 3 layers) ----
  hipMemsetAsync(cnt, 0, 4ull*N, stream);
  hipMemsetAsync(fill, 0, 4ull*N, stream);
  hipMemsetAsync(sum_attr, 0, 8ull*N, stream);
  k_count_edges<<<gE,TPB,0,stream>>>(dst, eattr, E, cnt, sum_attr);
  int nb1 = (N+1023)/1024;
  k_scan_tile<<<nb1,TPB,0,stream>>>(cnt, rs, bsum, N);
  k_scan_small<<<1,TPB,0,stream>>>(bsum, nb1);
  k_scan_add<<<gN,TPB,0,stream>>>(rs, bsum, N, E);
  k_scatter_edges<<<gE,TPB,0,stream>>>(src, dst, eattr, E, rs, fill, src_sorted, ea_sorted);

  // ---- layer 1 ----
  k_node_pre1<<<gN,TPB,0,stream>>>(group_ids, ord, emb,
      (const float*)d_in[9], (const float*)d_in[10], (const float*)d_in[11],
      xp, asrc, adst, N);
  int gagg = (N+3)/4;
  k_agg<<<gagg,TPB,0,stream>>>(xp, asrc, adst, rs, src_sorted, ea_sorted, cnt,
      (const float2*)sum_attr, (const float*)d_in[12], (const float*)d_in[13],
      (const float*)d_in[14], hbuf, N);
  // ---- layer 2 ----
  k_node_pre<<<gN,TPB,0,stream>>>(hbuf,
      (const float*)d_in[15], (const float*)d_in[16], (const float*)d_in[17],
      xp, asrc, adst, N);
  k_agg<<<gagg,TPB,0,stream>>>(xp, asrc, adst, rs, src_sorted, ea_sorted, cnt,
      (const float2*)sum_attr, (const float*)d_in[18], (const float*)d_in[19],
      (const float*)d_in[20], hbuf, N);
  // ---- layer 3 ----
  k_node_pre<<<gN,TPB,0,stream>>>(hbuf,
      (const float*)d_in[21], (const float*)d_in[22], (const float*)d_in[23],
      xp, asrc, adst, N);
  k_agg<<<gagg,TPB,0,stream>>>(xp, asrc, adst, rs, src_sorted, ea_sorted, cnt,
      (const float2*)sum_attr, (const float*)d_in[24], (const float*)d_in[25],
      (const float*)d_in[26], hbuf, N);

  // ---- pooling sort (aliases xp/src_sorted/ea_sorted — all dead now) ----
  hipMemsetAsync(cntP, 0, 4ull*P, stream);
  hipMemsetAsync(fillP, 0, 4ull*P, stream);
  k_count_idx<<<gZ,TPB,0,stream>>>(prow, NNZ, cntP);
  int nbP = (P+1023)/1024;
  k_scan_tile<<<nbP,TPB,0,stream>>>(cntP, rsP, bsum, P);
  k_scan_small<<<1,TPB,0,stream>>>(bsum, nbP);
  k_scan_add<<<gP,TPB,0,stream>>>(rsP, bsum, P, NNZ);
  k_scatter_pool<<<gZ,TPB,0,stream>>>(prow, pcol, pval, NNZ, rsP, fillP, col_sorted, val_sorted);

  // ---- pooling + fused head ----
  k_pool_head<<<(P+3)/4,TPB,0,stream>>>(hbuf, rsP, col_sorted, val_sorted,
      head_w1, head_b1, head_w2, head_b2, (float*)d_out, P);
}

// Round 2
// 1625.209 us; speedup vs baseline: 1.1687x; 1.1687x over previous
//
#include <hip/hip_runtime.h>

#define TPB 256

__device__ __forceinline__ float leaky02(float x){ return x > 0.f ? x : 0.2f*x; }

// ---------------- exclusive prefix scan (hierarchical) ----------------
__global__ void k_scan_tile(const int* __restrict__ in, int* __restrict__ out,
                            int* __restrict__ bsum, int n) {
  __shared__ int sh[TPB];
  int t = threadIdx.x;
  int base = blockIdx.x * (TPB*4) + t*4;
  int v0=0,v1=0,v2=0,v3=0;
  if (base+0 < n) v0 = in[base+0];
  if (base+1 < n) v1 = in[base+1];
  if (base+2 < n) v2 = in[base+2];
  if (base+3 < n) v3 = in[base+3];
  int tsum = v0+v1+v2+v3;
  sh[t] = tsum; __syncthreads();
  for (int off=1; off<TPB; off<<=1){
    int x = (t>=off) ? sh[t-off] : 0;
    __syncthreads();
    sh[t] += x;
    __syncthreads();
  }
  int incl = sh[t];
  int excl = incl - tsum;
  if (t == TPB-1) bsum[blockIdx.x] = incl;
  int run = excl;
  if (base+0 < n){ out[base+0] = run; run += v0; }
  if (base+1 < n){ out[base+1] = run; run += v1; }
  if (base+2 < n){ out[base+2] = run; run += v2; }
  if (base+3 < n){ out[base+3] = run; run += v3; }
}

__global__ void k_scan_small(int* __restrict__ a, int n) {
  __shared__ int sh[TPB];
  __shared__ int carry;
  int t = threadIdx.x;
  if (t==0) carry = 0;
  __syncthreads();
  for (int base=0; base<n; base+=TPB){
    int v = (base+t < n) ? a[base+t] : 0;
    sh[t] = v; __syncthreads();
    for (int off=1; off<TPB; off<<=1){
      int x = (t>=off)? sh[t-off]:0; __syncthreads();
      sh[t]+=x; __syncthreads();
    }
    int c0 = carry;
    if (base+t < n) a[base+t] = c0 + sh[t] - v;
    int tot = sh[TPB-1];
    __syncthreads();
    if (t==0) carry = c0 + tot;
    __syncthreads();
  }
}

__global__ void k_scan_add(int* __restrict__ out, const int* __restrict__ bsum,
                           int n, int total) {
  int i = blockIdx.x*TPB + threadIdx.x;
  if (i < n) out[i] += bsum[i >> 10];
  if (i == 0) out[n] = total;
}

// ---------------- counting / copy / scatter ----------------
__global__ void k_count(const int* __restrict__ seg, int n, int* __restrict__ cnt){
  int i = blockIdx.x*TPB+threadIdx.x;
  if (i < n) atomicAdd(&cnt[seg[i]], 1);
}

__global__ void k_copy_int(const int* __restrict__ s, int* __restrict__ d, int n){
  int i = blockIdx.x*TPB+threadIdx.x;
  if (i < n) d[i] = s[i];
}

// edge record: 16B {src, pad, ea.x, ea.y} -> one cacheline per random write
__global__ void k_scatter_edges(const int* __restrict__ src, const int* __restrict__ dst,
                                const float* __restrict__ eattr, int E,
                                int* __restrict__ next, int4* __restrict__ rec){
  int e = blockIdx.x*TPB+threadIdx.x;
  if (e>=E) return;
  int d = dst[e];
  int pos = atomicAdd(&next[d],1);
  float2 ea = ((const float2*)eattr)[e];
  int4 r;
  r.x = src[e];
  r.y = 0;
  r.z = __float_as_int(ea.x);
  r.w = __float_as_int(ea.y);
  rec[pos] = r;
}

// pool record: 8B {col, val}
__global__ void k_scatter_pool(const int* __restrict__ rows, const int* __restrict__ cols,
                               const float* __restrict__ vals, int n,
                               int* __restrict__ next, int2* __restrict__ rec){
  int i = blockIdx.x*TPB+threadIdx.x;
  if (i>=n) return;
  int r = rows[i];
  int pos = atomicAdd(&next[r],1);
  int2 q;
  q.x = cols[i];
  q.y = __float_as_int(vals[i]);
  rec[pos] = q;
}

// ---------------- per-node transform: xp = x@W, a_src, a_dst ----------------
__global__ __launch_bounds__(TPB) void k_node_pre1(
    const int* __restrict__ gid, const float* __restrict__ ord, const float* __restrict__ emb,
    const float* __restrict__ lin_w, const float* __restrict__ att_src, const float* __restrict__ att_dst,
    float* __restrict__ xp, float* __restrict__ asrc, float* __restrict__ adst, int N){
  __shared__ float W[20*32];
  __shared__ float As[32], Ad[32];
  for (int i=threadIdx.x; i<20*32; i+=TPB) W[i]=lin_w[i];
  if (threadIdx.x < 32){ As[threadIdx.x]=att_src[threadIdx.x]; Ad[threadIdx.x]=att_dst[threadIdx.x]; }
  __syncthreads();
  int n = blockIdx.x*TPB+threadIdx.x;
  if (n>=N) return;
  float x[20];
  int g = gid[n];
  #pragma unroll
  for (int k=0;k<16;k++) x[k]=emb[g*16+k];
  float4 o4 = ((const float4*)ord)[n];
  x[16]=o4.x; x[17]=o4.y; x[18]=o4.z; x[19]=o4.w;
  float acc[32];
  #pragma unroll
  for (int c=0;c<32;c++) acc[c]=0.f;
  #pragma unroll
  for (int k=0;k<20;k++){
    float xk=x[k];
    #pragma unroll
    for (int c=0;c<32;c++) acc[c] += xk*W[k*32+c];
  }
  float s0=0,s1=0,d0=0,d1=0;
  #pragma unroll
  for (int c=0;c<16;c++){
    s0+=acc[c]*As[c];      d0+=acc[c]*Ad[c];
    s1+=acc[16+c]*As[16+c]; d1+=acc[16+c]*Ad[16+c];
  }
  float4* xpo=(float4*)(xp + (size_t)n*32);
  #pragma unroll
  for (int q=0;q<8;q++) xpo[q]=make_float4(acc[4*q],acc[4*q+1],acc[4*q+2],acc[4*q+3]);
  asrc[2*n]=s0; asrc[2*n+1]=s1; adst[2*n]=d0; adst[2*n+1]=d1;
}

__global__ __launch_bounds__(TPB) void k_node_pre(
    const float* __restrict__ hin,
    const float* __restrict__ lin_w, const float* __restrict__ att_src, const float* __restrict__ att_dst,
    float* __restrict__ xp, float* __restrict__ asrc, float* __restrict__ adst, int N){
  __shared__ float W[32*32];
  __shared__ float As[32], Ad[32];
  for (int i=threadIdx.x; i<1024; i+=TPB) W[i]=lin_w[i];
  if (threadIdx.x < 32){ As[threadIdx.x]=att_src[threadIdx.x]; Ad[threadIdx.x]=att_dst[threadIdx.x]; }
  __syncthreads();
  int n = blockIdx.x*TPB+threadIdx.x;
  if (n>=N) return;
  float x[32];
  const float4* hi = (const float4*)(hin + (size_t)n*32);
  #pragma unroll
  for (int q=0;q<8;q++){ float4 v=hi[q]; x[4*q]=v.x; x[4*q+1]=v.y; x[4*q+2]=v.z; x[4*q+3]=v.w; }
  float acc[32];
  #pragma unroll
  for (int c=0;c<32;c++) acc[c]=0.f;
  #pragma unroll
  for (int k=0;k<32;k++){
    float xk=x[k];
    #pragma unroll
    for (int c=0;c<32;c++) acc[c] += xk*W[k*32+c];
  }
  float s0=0,s1=0,d0=0,d1=0;
  #pragma unroll
  for (int c=0;c<16;c++){
    s0+=acc[c]*As[c];       d0+=acc[c]*Ad[c];
    s1+=acc[16+c]*As[16+c]; d1+=acc[16+c]*Ad[16+c];
  }
  float4* xpo=(float4*)(xp + (size_t)n*32);
  #pragma unroll
  for (int q=0;q<8;q++) xpo[q]=make_float4(acc[4*q],acc[4*q+1],acc[4*q+2],acc[4*q+3]);
  asrc[2*n]=s0; asrc[2*n+1]=s1; adst[2*n]=d0; adst[2*n+1]=d1;
}

// ---------------- GAT aggregation: wave per node ----------------
// edge-attr sums for the self-loop mean are accumulated in-loop (free),
// self-loop term applied after the loop (softmax w/o max-sub is order-free).
__global__ __launch_bounds__(TPB) void k_agg(
    const float* __restrict__ xp, const float* __restrict__ asrc, const float* __restrict__ adst,
    const int* __restrict__ rs, const int4* __restrict__ rec,
    const float* __restrict__ edge_w, const float* __restrict__ att_edge,
    const float* __restrict__ bias, float* __restrict__ hout, int N)
{
  int n = blockIdx.x*4 + (threadIdx.x>>6);
  if (n >= N) return;
  int lane = threadIdx.x & 63;
  int c = lane & 31;
  int sub = lane >> 5;
  int h = c >> 4;
  float we0 = 0.f, we1 = 0.f;
  #pragma unroll
  for (int cc=0; cc<16; ++cc){
    float ae = att_edge[h*16+cc];
    we0 += edge_w[h*16+cc]*ae;
    we1 += edge_w[32+h*16+cc]*ae;
  }
  float adn = adst[2*n+h];
  float acc = 0.f, den = 0.f, sax = 0.f, say = 0.f;
  int jb = rs[n], je = rs[n+1];
  for (int j = jb + sub; j < je; j += 2){
    int4 r = rec[j];
    int s = r.x;
    float eax = __int_as_float(r.z), eay = __int_as_float(r.w);
    sax += eax; say += eay;
    float al = leaky02(asrc[2*s+h] + adn + eax*we0 + eay*we1);
    float p = __expf(al);
    acc += p * xp[(size_t)s*32+c];
    den += p;
  }
  sax += __shfl_xor(sax, 32);
  say += __shfl_xor(say, 32);
  if (sub == 0){
    int cn = je - jb;
    float inv = 1.0f / (float)(cn > 0 ? cn : 1);
    float al = leaky02(asrc[2*n+h] + adn + sax*inv*we0 + say*inv*we1);
    float p = __expf(al);
    acc += p * xp[(size_t)n*32+c];
    den += p;
  }
  acc += __shfl_xor(acc, 32);
  den += __shfl_xor(den, 32);
  if (sub == 0){
    hout[(size_t)n*32+c] = fmaxf(acc/(den + 1e-16f) + bias[c], 0.0f);
  }
}

// ---------------- pooling + fused MLP head: wave per pooled row ----------------
__global__ __launch_bounds__(TPB) void k_pool_head(
    const float* __restrict__ h3, const int* __restrict__ rsP,
    const int2* __restrict__ rec,
    const float* __restrict__ W1, const float* __restrict__ b1,
    const float* __restrict__ W2, const float* __restrict__ b2,
    float* __restrict__ out, int P){
  __shared__ float sW1[32*32];
  __shared__ float sb1[32], sW2[32];
  __shared__ float pool_s[4][32];
  for (int i=threadIdx.x;i<1024;i+=TPB) sW1[i]=W1[i];
  if (threadIdx.x<32){ sb1[threadIdx.x]=b1[threadIdx.x]; sW2[threadIdx.x]=W2[threadIdx.x]; }
  __syncthreads();
  int wslot = threadIdx.x >> 6;
  int lane = threadIdx.x & 63;
  int c = lane & 31, sub = lane >> 5;
  int p = blockIdx.x*4 + wslot;
  float acc = 0.f;
  if (p < P){
    int jb = rsP[p], je = rsP[p+1];
    for (int j=jb+sub; j<je; j+=2){
      int2 q = rec[j];
      acc += __int_as_float(q.y) * h3[(size_t)q.x*32 + c];
    }
  }
  acc += __shfl_xor(acc, 32);
  if (sub==0) pool_s[wslot][c] = acc;
  __syncthreads();
  if (p < P && sub==0){
    float hh = sb1[c];
    #pragma unroll
    for (int cc=0; cc<32; ++cc) hh += pool_s[wslot][cc]*sW1[cc*32+c];
    hh = fmaxf(hh, 0.f);
    float r = hh * sW2[c];
    #pragma unroll
    for (int m=16;m>=1;m>>=1) r += __shfl_xor(r, m);
    if (c==0) out[p] = r + b2[0];
  }
}

// ---------------- launch ----------------
extern "C" void kernel_launch(void* const* d_in, const int* in_sizes, int n_in,
                              void* d_out, int out_size, void* d_ws, size_t ws_size,
                              hipStream_t stream){
  const int*   group_ids = (const int*)d_in[0];
  const float* ord       = (const float*)d_in[1];
  const int*   eidx      = (const int*)d_in[2];
  const float* eattr     = (const float*)d_in[3];
  const int*   prow      = (const int*)d_in[4];
  const int*   pcol      = (const int*)d_in[5];
  const float* pval      = (const float*)d_in[6];
  const float* emb       = (const float*)d_in[8];
  const float* head_w1   = (const float*)d_in[27];
  const float* head_b1   = (const float*)d_in[28];
  const float* head_w2   = (const float*)d_in[29];
  const float* head_b2   = (const float*)d_in[30];

  int N   = in_sizes[0];
  int E   = in_sizes[2]/2;
  int NNZ = in_sizes[4];
  int P   = out_size;

  const int* src = eidx;
  const int* dst = eidx + E;

  char* w = (char*)d_ws;
  auto alloc = [&](size_t bytes)->char*{ char* p=w; w += (bytes+255)&~255ull; return p; };
  int*    cnt   = (int*)  alloc(4ull*N);
  int*    rs    = (int*)  alloc(4ull*(N+1));
  int*    next  = (int*)  alloc(4ull*N);
  int*    bsum  = (int*)  alloc(4ull*4096);
  int4*   recE  = (int4*) alloc(16ull*E);
  float*  xp    = (float*)alloc(4ull*32*N);
  float*  asrc  = (float*)alloc(8ull*N);
  float*  adst  = (float*)alloc(8ull*N);
  float*  hbuf  = (float*)alloc(4ull*32*N);

  // pool structures alias regions dead after layer-3 aggregation
  int*  cntP  = (int*)xp;          // P ints
  int*  nextP = cntP + P;          // P ints
  int*  rsP   = nextP + P;         // P+1 ints  (3*P*4 = 2.4MB << 12.8MB)
  int2* recP  = (int2*)recE;       // 8*NNZ <= 16*E

  int gE = (E+TPB-1)/TPB, gN = (N+TPB-1)/TPB, gZ = (NNZ+TPB-1)/TPB, gP = (P+TPB-1)/TPB;

  // ---- build dst-sorted edge structure (reused by all 3 layers) ----
  hipMemsetAsync(cnt, 0, 4ull*N, stream);
  k_count<<<gE,TPB,0,stream>>>(dst, E, cnt);
  int nb1 = (N+1023)/1024;
  k_scan_tile<<<nb1,TPB,0,stream>>>(cnt, rs, bsum, N);
  k_scan_small<<<1,TPB,0,stream>>>(bsum, nb1);
  k_scan_add<<<gN,TPB,0,stream>>>(rs, bsum, N, E);
  k_copy_int<<<gN,TPB,0,stream>>>(rs, next, N);
  k_scatter_edges<<<gE,TPB,0,stream>>>(src, dst, eattr, E, next, recE);

  // ---- layer 1 ----
  k_node_pre1<<<gN,TPB,0,stream>>>(group_ids, ord, emb,
      (const float*)d_in[9], (const float*)d_in[10], (const float*)d_in[11],
      xp, asrc, adst, N);
  int gagg = (N+3)/4;
  k_agg<<<gagg,TPB,0,stream>>>(xp, asrc, adst, rs, recE,
      (const float*)d_in[12], (const float*)d_in[13], (const float*)d_in[14], hbuf, N);
  // ---- layer 2 ----
  k_node_pre<<<gN,TPB,0,stream>>>(hbuf,
      (const float*)d_in[15], (const float*)d_in[16], (const float*)d_in[17],
      xp, asrc, adst, N);
  k_agg<<<gagg,TPB,0,stream>>>(xp, asrc, adst, rs, recE,
      (const float*)d_in[18], (const float*)d_in[19], (const float*)d_in[20], hbuf, N);
  // ---- layer 3 ----
  k_node_pre<<<gN,TPB,0,stream>>>(hbuf,
      (const float*)d_in[21], (const float*)d_in[22], (const float*)d_in[23],
      xp, asrc, adst, N);
  k_agg<<<gagg,TPB,0,stream>>>(xp, asrc, adst, rs, recE,
      (const float*)d_in[24], (const float*)d_in[25], (const float*)d_in[26], hbuf, N);

  // ---- pooling sort (aliases xp/recE — dead now) ----
  hipMemsetAsync(cntP, 0, 4ull*P, stream);
  k_count<<<gZ,TPB,0,stream>>>(prow, NNZ, cntP);
  int nbP = (P+1023)/1024;
  k_scan_tile<<<nbP,TPB,0,stream>>>(cntP, rsP, bsum, P);
  k_scan_small<<<1,TPB,0,stream>>>(bsum, nbP);
  k_scan_add<<<gP,TPB,0,stream>>>(rsP, bsum, P, NNZ);
  k_copy_int<<<gP,TPB,0,stream>>>(rsP, nextP, P);
  k_scatter_pool<<<gZ,TPB,0,stream>>>(prow, pcol, pval, NNZ, nextP, recP);

  // ---- pooling + fused head ----
  k_pool_head<<<(P+3)/4,TPB,0,stream>>>(hbuf, rsP, recP,
      head_w1, head_b1, head_w2, head_b2, (float*)d_out, P);
}